// Round 8
// baseline (211.303 us; speedup 1.0000x reference)
//
#include <hip/hip_runtime.h>

// Problem collapse: T=1, H=1, h0=c0=0 => Wh/f-gate dead; conv => pointwise
// matmul with Wx[(kh-1)//2,0,:,:]. 4 layers fused (split-bf16 MFMA).
// Block = 2 time-steps x 64 batches, 256 threads / 4 waves. REGISTER-SLIM
// restructure: m-outer MFMA loop -> acc = 3 gates (12 regs) + hv[16] buffer
// instead of acc[4][3]=48; total unified regs ~110-120 -> fits the
// __launch_bounds__(256,4) 128-reg cap WITHOUT spill (R3/R5 spilled because
// the old structure needed ~168). 32KB LDS. Target: 4 blocks/CU x 4 waves
// = 16 waves/CU (2x the 8-wave plateau of R2/R4/R7). Grid 1024 = exactly
// 4/CU, balanced. D1 partial fused as 5th layer; part = 16 MB fp32.

#define TSTEPS 2048
#define TPB 2            // t-tiles per block
#define NBLK 1024

typedef __attribute__((ext_vector_type(8))) short bf16x8;
typedef __attribute__((ext_vector_type(4))) float f32x4;

__device__ __forceinline__ unsigned short f2bf_rn(float f) {
    unsigned u = __float_as_uint(f);
    u += 0x7FFF + ((u >> 16) & 1);
    return (unsigned short)(u >> 16);
}
__device__ __forceinline__ float bf2f(unsigned short h) {
    return __uint_as_float(((unsigned)h) << 16);
}
__device__ __forceinline__ unsigned cvt_pk_bf16(float a, float b) {
    // D.lo16 = bf16_rne(a), D.hi16 = bf16_rne(b)  (RNE == f2bf_rn)
    unsigned r;
    asm("v_cvt_pk_bf16_f32 %0, %1, %2" : "=v"(r) : "v"(a), "v"(b));
    return r;
}
__device__ __forceinline__ float hsig(float x) {
    return fminf(fmaxf(fmaf(x, 0.2f, 0.5f), 0.0f), 1.0f);
}
__device__ __forceinline__ float tanh_f(float x) {
    float e = __expf(2.0f * x);
    return fmaf(-2.0f, __builtin_amdgcn_rcpf(e + 1.0f), 1.0f);
}
// Swizzled LDS index (shorts): row stride 64 (128B), XOR row&7 into the
// 16B-block index. b128 reads 16B-aligned; consecutive rows spread banks.
__device__ __forceinline__ int swz(int p, int c) {
    return p * 64 + ((((c >> 3) ^ (p & 7)) << 3) | (c & 7));
}

// Layer weights -> transposed split-bf16: per layer [hi:192x64][lo:192x64],
// row = g*64 + n. Grid 12 = 4 layers x 3 gates. Coalesced reads AND writes
// (LDS transpose).
__global__ __launch_bounds__(256) void prep_w(
    const float* __restrict__ W1, const float* __restrict__ W2,
    const float* __restrict__ W3, const float* __restrict__ W4,
    unsigned short* __restrict__ WT)
{
    __shared__ unsigned short Th[64][66], Tl[64][66];
    const int bid = blockIdx.x;
    const int ll = bid / 3;
    const int g  = bid - ll * 3;
    const float* W = (ll == 0) ? (W1 + 4 * 16384) :
                     (ll == 1) ? (W2 + 2 * 16384) :
                     (ll == 2) ? (W3 + 4 * 16384) : (W4 + 2 * 16384);
    const int gofs = (g == 0) ? 0 : ((g == 1) ? 128 : 192);
    unsigned short* hi = WT + ll * (2 * 192 * 64) + (g * 64) * 64;
    unsigned short* lo = hi + 192 * 64;
    const int n  = threadIdx.x & 63;
    const int wv = threadIdx.x >> 6;
    #pragma unroll
    for (int cc = 0; cc < 16; cc++) {
        int c = wv * 16 + cc;
        float w = W[c * 256 + gofs + n];       // coalesced (n contiguous)
        unsigned short h = f2bf_rn(w);
        Th[c][n] = h;
        Tl[c][n] = f2bf_rn(w - bf2f(h));
    }
    __syncthreads();
    // out[n*64 + c] = T[c][n]; thread t -> n = t>>2, c in [(t&3)*16, +16)
    const int on = threadIdx.x >> 2;
    const int oc = (threadIdx.x & 3) * 16;
    unsigned short bh[16], bl[16];
    #pragma unroll
    for (int i = 0; i < 16; i++) { bh[i] = Th[oc + i][on]; bl[i] = Tl[oc + i][on]; }
    #pragma unroll
    for (int q = 0; q < 2; q++) {
        *(uint4*)(hi + on * 64 + oc + q * 8) = *(const uint4*)&bh[q * 8];
        *(uint4*)(lo + on * 64 + oc + q * 8) = *(const uint4*)&bl[q * 8];
    }
}

// Fused 4-layer gated pointwise stack + D1 partial, split-bf16 MFMA 16x16x32.
// 4 waves; wave w owns output cols 16w..16w+15. m-outer loop: acc = 3 gates
// only (12 regs), results buffered in hv[4][4] until the barrier.
__global__ __launch_bounds__(256, 4) void fused_mfma(
    const float* __restrict__ x,
    const unsigned short* __restrict__ WT,
    const float* __restrict__ B1, const float* __restrict__ B2,
    const float* __restrict__ B3, const float* __restrict__ B4,
    const float* __restrict__ D1w, float* __restrict__ part)
{
    __shared__ __align__(16) unsigned short Hhi[TPB][4096];
    __shared__ __align__(16) unsigned short Hlo[TPB][4096];

    const int tid = threadIdx.x;
    const int lane = tid & 63;
    const int w = tid >> 6;
    const int tx = lane & 15;
    const int quad = lane >> 4;
    const int n = 16 * w + tx;
    const int tt0 = blockIdx.x * TPB;

    bf16x8 Bh[2][3], Bl[2][3];
    auto loadB = [&](int l) {
        const unsigned short* wl = WT + l * (2 * 192 * 64);
        #pragma unroll
        for (int ks = 0; ks < 2; ks++)
            #pragma unroll
            for (int g = 0; g < 3; g++) {
                const unsigned short* bp = wl + (g * 64 + n) * 64 + ks * 32 + quad * 8;
                Bh[ks][g] = *(const bf16x8*)bp;
                Bl[ks][g] = *(const bf16x8*)(bp + 192 * 64);
            }
    };

    loadB(0);   // overlaps x staging

    // Stage x for both tiles: per batch row p, 512B contiguous (2 t-chunks).
    {
        #pragma unroll
        for (int k = 0; k < 8; k++) {
            int lin4 = tid + k * 256;
            int p  = lin4 >> 5;        // batch row
            int q  = lin4 & 31;        // float4 index within the 512B row
            int it = q >> 4;
            int c0 = (q & 15) * 4;
            float4 v = *(const float4*)(x + (size_t)p * 131072 + (size_t)tt0 * 64 + (size_t)q * 4);
            unsigned hh01 = cvt_pk_bf16(v.x, v.y);
            unsigned hh23 = cvt_pk_bf16(v.z, v.w);
            unsigned ll01 = cvt_pk_bf16(v.x - __uint_as_float(hh01 << 16),
                                        v.y - __uint_as_float(hh01 & 0xffff0000u));
            unsigned ll23 = cvt_pk_bf16(v.z - __uint_as_float(hh23 << 16),
                                        v.w - __uint_as_float(hh23 & 0xffff0000u));
            *(uint2*)&Hhi[it][swz(p, c0)] = make_uint2(hh01, hh23);
            *(uint2*)&Hlo[it][swz(p, c0)] = make_uint2(ll01, ll23);
        }
    }
    __syncthreads();

    #pragma unroll 1
    for (int l = 0; l < 4; l++) {
        const float* Bb = (l == 0) ? B1 : (l == 1) ? B2 : (l == 2) ? B3 : B4;
        const float bi = Bb[n];
        const float bg = Bb[128 + n];
        const float bo = Bb[192 + n];

        #pragma unroll 1
        for (int it = 0; it < TPB; it++) {
            float hv[4][4];
            #pragma unroll
            for (int m = 0; m < 4; m++) {
                // A-frags for this row group (reads complete before barrier).
                bf16x8 Ah0 = *(const bf16x8*)&Hhi[it][swz(m * 16 + tx, quad * 8)];
                bf16x8 Al0 = *(const bf16x8*)&Hlo[it][swz(m * 16 + tx, quad * 8)];
                bf16x8 Ah1 = *(const bf16x8*)&Hhi[it][swz(m * 16 + tx, 32 + quad * 8)];
                bf16x8 Al1 = *(const bf16x8*)&Hlo[it][swz(m * 16 + tx, 32 + quad * 8)];

                f32x4 acc[3];
                acc[0] = (f32x4){bi, bi, bi, bi};
                acc[1] = (f32x4){bg, bg, bg, bg};
                acc[2] = (f32x4){bo, bo, bo, bo};
                #pragma unroll
                for (int g = 0; g < 3; g++) {
                    acc[g] = __builtin_amdgcn_mfma_f32_16x16x32_bf16(Ah0, Bh[0][g], acc[g], 0, 0, 0);
                    acc[g] = __builtin_amdgcn_mfma_f32_16x16x32_bf16(Ah0, Bl[0][g], acc[g], 0, 0, 0);
                    acc[g] = __builtin_amdgcn_mfma_f32_16x16x32_bf16(Al0, Bh[0][g], acc[g], 0, 0, 0);
                    acc[g] = __builtin_amdgcn_mfma_f32_16x16x32_bf16(Ah1, Bh[1][g], acc[g], 0, 0, 0);
                    acc[g] = __builtin_amdgcn_mfma_f32_16x16x32_bf16(Ah1, Bl[1][g], acc[g], 0, 0, 0);
                    acc[g] = __builtin_amdgcn_mfma_f32_16x16x32_bf16(Al1, Bh[1][g], acc[g], 0, 0, 0);
                }
                // Immediate per-m epilogue: acc dies here (12 regs, not 48).
                #pragma unroll
                for (int r = 0; r < 4; r++) {
                    float cs = hsig(acc[0][r]) * tanh_f(acc[1][r]);
                    hv[m][r] = hsig(acc[2][r]) * tanh_f(cs);
                }
            }

            // B-regs consumed for this layer's last tile -> prefetch next layer.
            if (it == TPB - 1 && l < 3) loadB(l + 1);

            __syncthreads();   // all reads of Hbuf[it] done -> safe to overwrite
            #pragma unroll
            for (int m = 0; m < 4; m++)
                #pragma unroll
                for (int rp = 0; rp < 2; rp++) {
                    float a = hv[m][2 * rp], b = hv[m][2 * rp + 1];
                    int p0 = m * 16 + quad * 4 + 2 * rp;
                    unsigned pk = cvt_pk_bf16(a, b);
                    Hhi[it][swz(p0, n)]     = (unsigned short)(pk & 0xffffu);
                    Hhi[it][swz(p0 + 1, n)] = (unsigned short)(pk >> 16);
                    unsigned lk = cvt_pk_bf16(a - __uint_as_float(pk << 16),
                                              b - __uint_as_float(pk & 0xffff0000u));
                    Hlo[it][swz(p0, n)]     = (unsigned short)(lk & 0xffffu);
                    Hlo[it][swz(p0 + 1, n)] = (unsigned short)(lk >> 16);
                }
            // No trailing barrier: next tile touches the other buffer;
            // next layer's read of this tile is fenced by the other tile's barrier.
        }
    }

    // 5th layer: D1 partial  accD[b][j] += sum_it sum_c h4[it][b][c]*D1w[(tt0+it)*64+c][j]
    const float* Wd = D1w + (size_t)tt0 * 64 * 64;
    float dv[16];
    #pragma unroll
    for (int ks = 0; ks < 2; ks++)
        #pragma unroll
        for (int jj = 0; jj < 8; jj++)
            dv[ks * 8 + jj] = Wd[(ks * 32 + quad * 8 + jj) * 64 + n];
    __syncthreads();   // fence W(l=3, it=TPB-1); dv loads issued before it

    f32x4 accD[4];
    #pragma unroll
    for (int m = 0; m < 4; m++) accD[m] = (f32x4){0.0f, 0.0f, 0.0f, 0.0f};

    #pragma unroll
    for (int it = 0; it < TPB; it++) {
        float dn[16];
        if (it < TPB - 1) {
            #pragma unroll
            for (int ks = 0; ks < 2; ks++)
                #pragma unroll
                for (int jj = 0; jj < 8; jj++)
                    dn[ks * 8 + jj] = Wd[(it + 1) * 4096 + (ks * 32 + quad * 8 + jj) * 64 + n];
        }
        bf16x8 Dh[2], Dl[2];
        #pragma unroll
        for (int ks = 0; ks < 2; ks++) {
            union { bf16x8 v8; unsigned u[4]; } Hu, Lu;
            #pragma unroll
            for (int q2 = 0; q2 < 4; q2++) {
                float a = dv[ks * 8 + 2 * q2], b = dv[ks * 8 + 2 * q2 + 1];
                unsigned hp = cvt_pk_bf16(a, b);
                Hu.u[q2] = hp;
                Lu.u[q2] = cvt_pk_bf16(a - __uint_as_float(hp << 16),
                                       b - __uint_as_float(hp & 0xffff0000u));
            }
            Dh[ks] = Hu.v8;
            Dl[ks] = Lu.v8;
        }
        #pragma unroll
        for (int ks = 0; ks < 2; ks++)
            #pragma unroll
            for (int m = 0; m < 4; m++) {
                bf16x8 Ah = *(const bf16x8*)&Hhi[it][swz(m * 16 + tx, ks * 32 + quad * 8)];
                bf16x8 Al = *(const bf16x8*)&Hlo[it][swz(m * 16 + tx, ks * 32 + quad * 8)];
                accD[m] = __builtin_amdgcn_mfma_f32_16x16x32_bf16(Ah, Dh[ks], accD[m], 0, 0, 0);
                accD[m] = __builtin_amdgcn_mfma_f32_16x16x32_bf16(Ah, Dl[ks], accD[m], 0, 0, 0);
                accD[m] = __builtin_amdgcn_mfma_f32_16x16x32_bf16(Al, Dh[ks], accD[m], 0, 0, 0);
            }
        if (it < TPB - 1) {
            #pragma unroll
            for (int z = 0; z < 16; z++) dv[z] = dn[z];
        }
    }

    // Coalesced part write via padded LDS transpose (stride 66).
    __syncthreads();   // Hbuf dead
    float* LP = (float*)&Hhi[0][0];   // 64*66*4 = 16.9 KB (Hhi + start of Hlo, both dead)
    #pragma unroll
    for (int m = 0; m < 4; m++)
        #pragma unroll
        for (int r = 0; r < 4; r++)
            LP[(m * 16 + quad * 4 + r) * 66 + n] = accD[m][r];
    __syncthreads();
    float* dst = part + (size_t)blockIdx.x * 4096;
    #pragma unroll
    for (int k = 0; k < 8; k++) {
        int lin2 = tid + k * 256;
        int row = lin2 >> 5;
        int c0 = (lin2 & 31) * 2;
        float2 val = *(const float2*)&LP[row * 66 + c0];
        *(float2*)&dst[row * 64 + c0] = val;
    }
}

// Fused reduce: per batch b, sum 1024 block-partials + D1b, relu, dot D2w, +D2b.
__global__ __launch_bounds__(1024) void reduce_fused(
    const float* __restrict__ part, const float* __restrict__ D1b,
    const float* __restrict__ D2w, const float* __restrict__ D2b,
    float* __restrict__ out)
{
    __shared__ float red[16][64];
    const int b = blockIdx.x;
    const int t = threadIdx.x;
    const int j = t & 63, s = t >> 6;
    float acc = 0.0f;
    #pragma unroll 8
    for (int m = 0; m < 64; m++)
        acc += part[(size_t)(s + 16 * m) * 4096 + b * 64 + j];
    red[s][j] = acc;
    __syncthreads();
    if (t < 64) {
        float v = D1b[t];
        #pragma unroll
        for (int s2 = 0; s2 < 16; s2++) v += red[s2][t];
        v = fmaxf(v, 0.0f) * D2w[t];
        #pragma unroll
        for (int off = 32; off > 0; off >>= 1)
            v += __shfl_down(v, off, 64);
        if (t == 0) out[b] = v + D2b[0];
    }
}

extern "C" void kernel_launch(void* const* d_in, const int* in_sizes, int n_in,
                              void* d_out, int out_size, void* d_ws, size_t ws_size,
                              hipStream_t stream) {
    (void)in_sizes; (void)n_in; (void)out_size; (void)ws_size;
    const float* x   = (const float*)d_in[0];
    const float* W1x = (const float*)d_in[1];
    const float* b1  = (const float*)d_in[3];
    const float* W2x = (const float*)d_in[4];
    const float* b2  = (const float*)d_in[6];
    const float* W3x = (const float*)d_in[7];
    const float* b3  = (const float*)d_in[9];
    const float* W4x = (const float*)d_in[10];
    const float* b4  = (const float*)d_in[12];
    const float* D1w = (const float*)d_in[13];
    const float* D1b = (const float*)d_in[14];
    const float* D2w = (const float*)d_in[15];
    const float* D2b = (const float*)d_in[16];
    float* out = (float*)d_out;

    float* part = (float*)d_ws;                                  // 1024*4096*4 = 16 MB
    unsigned short* WT = (unsigned short*)(part + (size_t)NBLK * 4096);  // 192 KB

    prep_w<<<dim3(12), dim3(256), 0, stream>>>(W1x, W2x, W3x, W4x, WT);
    fused_mfma<<<dim3(NBLK), dim3(256), 0, stream>>>(
        x, WT, b1, b2, b3, b4, D1w, part);
    reduce_fused<<<dim3(64), dim3(1024), 0, stream>>>(part, D1b, D2w, D2b, out);
}

// Round 9
// 171.791 us; speedup vs baseline: 1.2300x; 1.2300x over previous
//
#include <hip/hip_runtime.h>

// Problem collapse: T=1, H=1, h0=c0=0 => Wh/f-gate dead; conv => pointwise
// matmul with Wx[(kh-1)//2,0,:,:]. 4 layers fused (split-bf16 MFMA).
// Block = 4 consecutive time-steps x 64 batches, 256 threads / 4 waves.
// == R2 structure (proven 64us fused, zero spill) with ONE change:
// epilogue moved AFTER the barrier (A-reads are complete at the barrier;
// acc crosses it and dies per-m) -> hv[16] buffer deleted, peak unified regs
// ~168 -> ~152, and __launch_bounds__(256,3) (cap 170) to let the allocator
// reach 3 waves/SIMD = 12 waves/CU. (Caps <=128 spilled 3x: R3/R5/R8.)
// D1 partial fused as 5th layer; part = 8 MB fp32, coalesced via
// padded-LDS transpose.

#define TSTEPS 2048
#define TPB 4            // t-tiles per block
#define NBLK 512

typedef __attribute__((ext_vector_type(8))) short bf16x8;
typedef __attribute__((ext_vector_type(4))) float f32x4;

__device__ __forceinline__ unsigned short f2bf_rn(float f) {
    unsigned u = __float_as_uint(f);
    u += 0x7FFF + ((u >> 16) & 1);
    return (unsigned short)(u >> 16);
}
__device__ __forceinline__ float bf2f(unsigned short h) {
    return __uint_as_float(((unsigned)h) << 16);
}
__device__ __forceinline__ unsigned cvt_pk_bf16(float a, float b) {
    // D.lo16 = bf16_rne(a), D.hi16 = bf16_rne(b)  (RNE == f2bf_rn)
    unsigned r;
    asm("v_cvt_pk_bf16_f32 %0, %1, %2" : "=v"(r) : "v"(a), "v"(b));
    return r;
}
__device__ __forceinline__ float hsig(float x) {
    return fminf(fmaxf(fmaf(x, 0.2f, 0.5f), 0.0f), 1.0f);
}
__device__ __forceinline__ float tanh_f(float x) {
    float e = __expf(2.0f * x);
    return fmaf(-2.0f, __builtin_amdgcn_rcpf(e + 1.0f), 1.0f);
}
// Swizzled LDS index (shorts): row stride 64 (128B), XOR row&7 into the
// 16B-block index. b128 reads 16B-aligned; consecutive rows spread banks.
__device__ __forceinline__ int swz(int p, int c) {
    return p * 64 + ((((c >> 3) ^ (p & 7)) << 3) | (c & 7));
}

// Layer weights -> transposed split-bf16: per layer [hi:192x64][lo:192x64],
// row = g*64 + n. Grid 12 = 4 layers x 3 gates. Coalesced reads AND writes
// (LDS transpose).
__global__ __launch_bounds__(256) void prep_w(
    const float* __restrict__ W1, const float* __restrict__ W2,
    const float* __restrict__ W3, const float* __restrict__ W4,
    unsigned short* __restrict__ WT)
{
    __shared__ unsigned short Th[64][66], Tl[64][66];
    const int bid = blockIdx.x;
    const int ll = bid / 3;
    const int g  = bid - ll * 3;
    const float* W = (ll == 0) ? (W1 + 4 * 16384) :
                     (ll == 1) ? (W2 + 2 * 16384) :
                     (ll == 2) ? (W3 + 4 * 16384) : (W4 + 2 * 16384);
    const int gofs = (g == 0) ? 0 : ((g == 1) ? 128 : 192);
    unsigned short* hi = WT + ll * (2 * 192 * 64) + (g * 64) * 64;
    unsigned short* lo = hi + 192 * 64;
    const int n  = threadIdx.x & 63;
    const int wv = threadIdx.x >> 6;
    #pragma unroll
    for (int cc = 0; cc < 16; cc++) {
        int c = wv * 16 + cc;
        float w = W[c * 256 + gofs + n];       // coalesced (n contiguous)
        unsigned short h = f2bf_rn(w);
        Th[c][n] = h;
        Tl[c][n] = f2bf_rn(w - bf2f(h));
    }
    __syncthreads();
    // out[n*64 + c] = T[c][n]; thread t -> n = t>>2, c in [(t&3)*16, +16)
    const int on = threadIdx.x >> 2;
    const int oc = (threadIdx.x & 3) * 16;
    unsigned short bh[16], bl[16];
    #pragma unroll
    for (int i = 0; i < 16; i++) { bh[i] = Th[oc + i][on]; bl[i] = Tl[oc + i][on]; }
    #pragma unroll
    for (int q = 0; q < 2; q++) {
        *(uint4*)(hi + on * 64 + oc + q * 8) = *(const uint4*)&bh[q * 8];
        *(uint4*)(lo + on * 64 + oc + q * 8) = *(const uint4*)&bl[q * 8];
    }
}

// Fused 4-layer gated pointwise stack + D1 partial, split-bf16 MFMA 16x16x32.
// 4 waves; wave w owns output cols 16w..16w+15, m-loop over all 4 row tiles.
__global__ __launch_bounds__(256, 3) void fused_mfma(
    const float* __restrict__ x,
    const unsigned short* __restrict__ WT,
    const float* __restrict__ B1, const float* __restrict__ B2,
    const float* __restrict__ B3, const float* __restrict__ B4,
    const float* __restrict__ D1w, float* __restrict__ part)
{
    __shared__ __align__(16) unsigned short Hhi[TPB][4096];
    __shared__ __align__(16) unsigned short Hlo[TPB][4096];

    const int tid = threadIdx.x;
    const int lane = tid & 63;
    const int w = tid >> 6;
    const int tx = lane & 15;
    const int quad = lane >> 4;
    const int n = 16 * w + tx;
    const int tt0 = blockIdx.x * TPB;

    bf16x8 Bh[2][3], Bl[2][3];
    auto loadB = [&](int l) {
        const unsigned short* wl = WT + l * (2 * 192 * 64);
        #pragma unroll
        for (int ks = 0; ks < 2; ks++)
            #pragma unroll
            for (int g = 0; g < 3; g++) {
                const unsigned short* bp = wl + (g * 64 + n) * 64 + ks * 32 + quad * 8;
                Bh[ks][g] = *(const bf16x8*)bp;
                Bl[ks][g] = *(const bf16x8*)(bp + 192 * 64);
            }
    };

    loadB(0);   // overlaps x staging

    // Stage x for all 4 tiles: per batch row p, 1KB contiguous (4 t-chunks).
    {
        #pragma unroll
        for (int k = 0; k < 16; k++) {
            int lin4 = tid + k * 256;
            int p  = lin4 >> 6;        // batch row
            int q  = lin4 & 63;        // float4 index within the 1KB row
            int it = q >> 4;
            int c0 = (q & 15) * 4;
            float4 v = *(const float4*)(x + (size_t)p * 131072 + (size_t)tt0 * 64 + (size_t)q * 4);
            unsigned hh01 = cvt_pk_bf16(v.x, v.y);
            unsigned hh23 = cvt_pk_bf16(v.z, v.w);
            unsigned ll01 = cvt_pk_bf16(v.x - __uint_as_float(hh01 << 16),
                                        v.y - __uint_as_float(hh01 & 0xffff0000u));
            unsigned ll23 = cvt_pk_bf16(v.z - __uint_as_float(hh23 << 16),
                                        v.w - __uint_as_float(hh23 & 0xffff0000u));
            *(uint2*)&Hhi[it][swz(p, c0)] = make_uint2(hh01, hh23);
            *(uint2*)&Hlo[it][swz(p, c0)] = make_uint2(ll01, ll23);
        }
    }
    __syncthreads();

    #pragma unroll 1
    for (int l = 0; l < 4; l++) {
        const float* Bb = (l == 0) ? B1 : (l == 1) ? B2 : (l == 2) ? B3 : B4;
        const float bi = Bb[n];
        const float bg = Bb[128 + n];
        const float bo = Bb[192 + n];

        #pragma unroll 1
        for (int it = 0; it < TPB; it++) {
            f32x4 acc[4][3];
            #pragma unroll
            for (int m = 0; m < 4; m++) {
                acc[m][0] = (f32x4){bi, bi, bi, bi};
                acc[m][1] = (f32x4){bg, bg, bg, bg};
                acc[m][2] = (f32x4){bo, bo, bo, bo};
            }

            #pragma unroll
            for (int ks = 0; ks < 2; ks++)
                #pragma unroll
                for (int m = 0; m < 4; m++) {
                    bf16x8 Ah = *(const bf16x8*)&Hhi[it][swz(m * 16 + tx, ks * 32 + quad * 8)];
                    bf16x8 Al = *(const bf16x8*)&Hlo[it][swz(m * 16 + tx, ks * 32 + quad * 8)];
                    #pragma unroll
                    for (int g = 0; g < 3; g++) {
                        acc[m][g] = __builtin_amdgcn_mfma_f32_16x16x32_bf16(Ah, Bh[ks][g], acc[m][g], 0, 0, 0);
                        acc[m][g] = __builtin_amdgcn_mfma_f32_16x16x32_bf16(Ah, Bl[ks][g], acc[m][g], 0, 0, 0);
                        acc[m][g] = __builtin_amdgcn_mfma_f32_16x16x32_bf16(Al, Bh[ks][g], acc[m][g], 0, 0, 0);
                    }
                }

            // B-regs consumed for this layer's last tile -> prefetch next layer.
            if (it == TPB - 1 && l < 3) loadB(l + 1);

            __syncthreads();   // all A-reads of Hbuf[it] done -> safe to overwrite.
            // Epilogue AFTER the barrier: no hv buffer; acc dies per-m.
            #pragma unroll
            for (int m = 0; m < 4; m++) {
                float hv[4];
                #pragma unroll
                for (int r = 0; r < 4; r++) {
                    float cs = hsig(acc[m][0][r]) * tanh_f(acc[m][1][r]);
                    hv[r] = hsig(acc[m][2][r]) * tanh_f(cs);
                }
                #pragma unroll
                for (int rp = 0; rp < 2; rp++) {
                    float a = hv[2 * rp], b = hv[2 * rp + 1];
                    int p0 = m * 16 + quad * 4 + 2 * rp;
                    unsigned pk = cvt_pk_bf16(a, b);
                    Hhi[it][swz(p0, n)]     = (unsigned short)(pk & 0xffffu);
                    Hhi[it][swz(p0 + 1, n)] = (unsigned short)(pk >> 16);
                    unsigned lk = cvt_pk_bf16(a - __uint_as_float(pk << 16),
                                              b - __uint_as_float(pk & 0xffff0000u));
                    Hlo[it][swz(p0, n)]     = (unsigned short)(lk & 0xffffu);
                    Hlo[it][swz(p0 + 1, n)] = (unsigned short)(lk >> 16);
                }
            }
            // No trailing barrier: next tile touches a different buffer;
            // next layer's read of this tile is fenced by later tile barriers.
        }
    }

    // 5th layer: D1 partial  accD[b][j] += sum_it sum_c h4[it][b][c]*D1w[(tt0+it)*64+c][j]
    const float* Wd = D1w + (size_t)tt0 * 64 * 64;
    float dv[16];
    #pragma unroll
    for (int ks = 0; ks < 2; ks++)
        #pragma unroll
        for (int jj = 0; jj < 8; jj++)
            dv[ks * 8 + jj] = Wd[(ks * 32 + quad * 8 + jj) * 64 + n];
    __syncthreads();   // fence W(l=3, it=TPB-1); dv loads issued before it

    f32x4 accD[4];
    #pragma unroll
    for (int m = 0; m < 4; m++) accD[m] = (f32x4){0.0f, 0.0f, 0.0f, 0.0f};

    #pragma unroll
    for (int it = 0; it < TPB; it++) {
        float dn[16];
        if (it < TPB - 1) {
            #pragma unroll
            for (int ks = 0; ks < 2; ks++)
                #pragma unroll
                for (int jj = 0; jj < 8; jj++)
                    dn[ks * 8 + jj] = Wd[(it + 1) * 4096 + (ks * 32 + quad * 8 + jj) * 64 + n];
        }
        bf16x8 Dh[2], Dl[2];
        #pragma unroll
        for (int ks = 0; ks < 2; ks++) {
            union { bf16x8 v8; unsigned u[4]; } Hu, Lu;
            #pragma unroll
            for (int q2 = 0; q2 < 4; q2++) {
                float a = dv[ks * 8 + 2 * q2], b = dv[ks * 8 + 2 * q2 + 1];
                unsigned hp = cvt_pk_bf16(a, b);
                Hu.u[q2] = hp;
                Lu.u[q2] = cvt_pk_bf16(a - __uint_as_float(hp << 16),
                                       b - __uint_as_float(hp & 0xffff0000u));
            }
            Dh[ks] = Hu.v8;
            Dl[ks] = Lu.v8;
        }
        #pragma unroll
        for (int ks = 0; ks < 2; ks++)
            #pragma unroll
            for (int m = 0; m < 4; m++) {
                bf16x8 Ah = *(const bf16x8*)&Hhi[it][swz(m * 16 + tx, ks * 32 + quad * 8)];
                bf16x8 Al = *(const bf16x8*)&Hlo[it][swz(m * 16 + tx, ks * 32 + quad * 8)];
                accD[m] = __builtin_amdgcn_mfma_f32_16x16x32_bf16(Ah, Dh[ks], accD[m], 0, 0, 0);
                accD[m] = __builtin_amdgcn_mfma_f32_16x16x32_bf16(Ah, Dl[ks], accD[m], 0, 0, 0);
                accD[m] = __builtin_amdgcn_mfma_f32_16x16x32_bf16(Al, Dh[ks], accD[m], 0, 0, 0);
            }
        if (it < TPB - 1) {
            #pragma unroll
            for (int z = 0; z < 16; z++) dv[z] = dn[z];
        }
    }

    // Coalesced part write via padded LDS transpose (stride 66).
    __syncthreads();   // Hbuf dead
    float* LP = (float*)&Hhi[0][0];   // 64*66*4 = 16.9 KB
    #pragma unroll
    for (int m = 0; m < 4; m++)
        #pragma unroll
        for (int r = 0; r < 4; r++)
            LP[(m * 16 + quad * 4 + r) * 66 + n] = accD[m][r];
    __syncthreads();
    float* dst = part + (size_t)blockIdx.x * 4096;
    #pragma unroll
    for (int k = 0; k < 8; k++) {
        int lin2 = tid + k * 256;
        int row = lin2 >> 5;
        int c0 = (lin2 & 31) * 2;
        float2 val = *(const float2*)&LP[row * 66 + c0];
        *(float2*)&dst[row * 64 + c0] = val;
    }
}

// Fused reduce: per batch b, sum 512 block-partials + D1b, relu, dot D2w, +D2b.
__global__ __launch_bounds__(1024) void reduce_fused(
    const float* __restrict__ part, const float* __restrict__ D1b,
    const float* __restrict__ D2w, const float* __restrict__ D2b,
    float* __restrict__ out)
{
    __shared__ float red[16][64];
    const int b = blockIdx.x;
    const int t = threadIdx.x;
    const int j = t & 63, s = t >> 6;
    float acc = 0.0f;
    #pragma unroll 8
    for (int m = 0; m < 32; m++)
        acc += part[(size_t)(s + 16 * m) * 4096 + b * 64 + j];
    red[s][j] = acc;
    __syncthreads();
    if (t < 64) {
        float v = D1b[t];
        #pragma unroll
        for (int s2 = 0; s2 < 16; s2++) v += red[s2][t];
        v = fmaxf(v, 0.0f) * D2w[t];
        #pragma unroll
        for (int off = 32; off > 0; off >>= 1)
            v += __shfl_down(v, off, 64);
        if (t == 0) out[b] = v + D2b[0];
    }
}

extern "C" void kernel_launch(void* const* d_in, const int* in_sizes, int n_in,
                              void* d_out, int out_size, void* d_ws, size_t ws_size,
                              hipStream_t stream) {
    (void)in_sizes; (void)n_in; (void)out_size; (void)ws_size;
    const float* x   = (const float*)d_in[0];
    const float* W1x = (const float*)d_in[1];
    const float* b1  = (const float*)d_in[3];
    const float* W2x = (const float*)d_in[4];
    const float* b2  = (const float*)d_in[6];
    const float* W3x = (const float*)d_in[7];
    const float* b3  = (const float*)d_in[9];
    const float* W4x = (const float*)d_in[10];
    const float* b4  = (const float*)d_in[12];
    const float* D1w = (const float*)d_in[13];
    const float* D1b = (const float*)d_in[14];
    const float* D2w = (const float*)d_in[15];
    const float* D2b = (const float*)d_in[16];
    float* out = (float*)d_out;

    float* part = (float*)d_ws;                                  // 512*4096*4 = 8 MB
    unsigned short* WT = (unsigned short*)(part + (size_t)NBLK * 4096);  // 192 KB

    prep_w<<<dim3(12), dim3(256), 0, stream>>>(W1x, W2x, W3x, W4x, WT);
    fused_mfma<<<dim3(NBLK), dim3(256), 0, stream>>>(
        x, WT, b1, b2, b3, b4, D1w, part);
    reduce_fused<<<dim3(64), dim3(1024), 0, stream>>>(part, D1b, D2w, D2b, out);
}